// Round 1
// baseline (748.575 us; speedup 1.0000x reference)
//
#include <hip/hip_runtime.h>
#include <cstdint>
#include <cstddef>

// Problem constants
#define B_   2
#define P_   8192
#define NN_  24
#define C1_  32
#define C2_  32
#define K_   13
#define A_   12
#define DR_  384   // C2_*A_  (rows: d*12+r)
#define CA_  384   // C1_*A_  (cols: c*12+a)
#define PT_  32    // p-tile per block
#define BPAD 408   // 384 + 24 pad: stride 204 dwords ≡ 12 (mod 32) -> 2-way (free) b128 reads

typedef __attribute__((ext_vector_type(8))) short short8;
typedef __attribute__((ext_vector_type(4))) float floatx4;

__device__ __forceinline__ unsigned short f2bf(float f) {
    union { float f; unsigned int u; } v; v.f = f;
    unsigned int u = v.u;
    return (unsigned short)((u + 0x7fffu + ((u >> 16) & 1u)) >> 16); // RNE
}

// ---------------- prep kernels ----------------

// WT2[k][dr][ca] = bf16( W[d,c,m] * k_pos_w[d,m] ), unpadded row-major (768 B rows).
// m = idx_map[ tivr[r,k]*12 + tir[r,a] ], dr=d*12+r, ca=c*12+a.
__global__ void build_wt(const float* __restrict__ W, const float* __restrict__ kpw,
                         const int* __restrict__ idx_map, const int* __restrict__ tivr,
                         const int* __restrict__ tir, unsigned short* __restrict__ WT2) {
    int id = blockIdx.x * 256 + threadIdx.x;
    const int TOT = K_ * DR_ * CA_;
    if (id >= TOT) return;
    int ca = id % CA_;
    int t1 = id / CA_;
    int dr = t1 % DR_;
    int k  = t1 / DR_;
    int d = dr / 12, r = dr % 12;
    int c = ca / 12, a = ca % 12;
    int kk = tivr[r * K_ + k];
    int ia = tir[r * A_ + a];
    int m  = idx_map[kk * A_ + ia];
    WT2[id] = f2bf(W[(d * C1_ + c) * 36 + m] * kpw[d * 36 + m]);
}

__global__ void build_md(const int* __restrict__ nbr, const float* __restrict__ verts,
                         float* __restrict__ md) {
    int t = blockIdx.x * 256 + threadIdx.x;
    if (t >= B_ * P_) return;
    const float* vp = verts + (size_t)t * 3;
    float vx = vp[0], vy = vp[1], vz = vp[2];
    int b = t / P_;
    const int* np = nbr + (size_t)t * NN_;
    float ax = 0.f, ay = 0.f, az = 0.f;
    for (int n = 0; n < NN_; n++) {
        int j = np[n];
        const float* vq = verts + ((size_t)b * P_ + j) * 3;
        float dx = vq[0] - vx, dy = vq[1] - vy, dz = vq[2] - vz;
        float nn = sqrtf(dx * dx + dy * dy + dz * dz);
        float inv = 1.f / fmaxf(nn, 1e-12f);
        ax += dx * inv; ay += dy * inv; az += dz * inv;
    }
    const float s = 1.f / 24.f;
    md[t * 3 + 0] = ax * s; md[t * 3 + 1] = ay * s; md[t * 3 + 2] = az * s;
}

__global__ void build_kpo(const float* __restrict__ kpw, const int* __restrict__ idx_map,
                          const float* __restrict__ vs, float* __restrict__ kpo) {
    int t = blockIdx.x * 64 + threadIdx.x;
    if (t >= C2_ * K_) return;
    int d = t / K_, k = t % K_;
    float x = 0.f, y = 0.f, z = 0.f;
    for (int a = 0; a < A_; a++) {
        float w = kpw[d * 36 + idx_map[k * A_ + a]];
        x += w * vs[a * 3 + 0]; y += w * vs[a * 3 + 1]; z += w * vs[a * 3 + 2];
    }
    float nn = sqrtf(x * x + y * y + z * z);
    float inv = 1.f / fmaxf(nn, 1e-12f);
    kpo[t * 3 + 0] = x * inv; kpo[t * 3 + 1] = y * inv; kpo[t * 3 + 2] = z * inv;
}

__global__ void build_be(const float* __restrict__ bias, const int* __restrict__ lvl,
                         const int* __restrict__ tivr, float* __restrict__ be) {
    int t = blockIdx.x * 64 + threadIdx.x;
    if (t >= DR_) return;
    int d = t / 12, r = t % 12;
    float s = 0.f;
    for (int k = 0; k < K_; k++) s += bias[d * 5 + lvl[tivr[r * K_ + k]]];
    be[t] = s;
}

// ---------------- main fused kernel ----------------
// grid = 512 blocks (b x 256 p-tiles of 32), 256 threads (4 waves), 2 blocks/CU.
// fm loads + out stores are NON-TEMPORAL (zero-reuse streams) so WT2 (3.8 MB)
// stays resident in each XCD's 4 MiB L2 -> A-fragment loads become L2 hits.
// A-fragments prefetched 2 chunks deep (ring of 3) to hide L2-hit latency.
__global__ __launch_bounds__(256, 2) void main_gemm(
    const float* __restrict__ fm, const unsigned short* __restrict__ WT,
    const float* __restrict__ md, const float* __restrict__ kpo,
    const float* __restrict__ be, float* __restrict__ out) {

    __shared__ __attribute__((aligned(16))) unsigned short Bs[2][PT_][BPAD]; // 52224 B
    __shared__ float pwS[2][C2_][PT_ + 1];  // [buf][d][p] +1 pad -> <=2-way banks, 8448 B
    __shared__ float mdS[PT_][3];           // 384 B
    __shared__ float kpoS[C2_ * K_ * 3];    // 4992 B
    __shared__ float biasS[DR_];            // 1536 B

    const int tid  = threadIdx.x;
    const int bid  = blockIdx.x;
    const int b    = bid >> 8;
    const int p0   = (bid & 255) << 5;
    const int lane = tid & 63;
    const int wid  = tid >> 6;
    const int rowm = lane & 15;
    const int quad = lane >> 4;

    // this thread's fm-slice decomposition (12 float4 per thread, coalesced)
    floatx4 pf[12];
    int pf_c[12], pf_jj[12];
    #pragma unroll
    for (int j = 0; j < 12; j++) {
        int f = j * 256 + tid;
        pf_c[j]  = f / 96;
        pf_jj[j] = f - pf_c[j] * 96;
    }

    // non-temporal: fm is a zero-reuse stream; do not pollute L2 (keeps WT resident)
    #define LOAD_PF(kk)                                                                  \
        { _Pragma("unroll")                                                              \
          for (int j = 0; j < 12; j++) {                                                 \
            const floatx4* src = (const floatx4*)(fm +                                   \
                ((((size_t)b * C1_ + pf_c[j]) * K_ + (kk)) * P_ + p0) * A_) + pf_jj[j];  \
            pf[j] = __builtin_nontemporal_load(src);                                     \
          } }

    #define STORE_PF(bufw)                                                               \
        { _Pragma("unroll")                                                              \
          for (int j = 0; j < 12; j++) {                                                 \
            int pl = pf_jj[j] / 3, aseg = (pf_jj[j] - pl * 3) * 4;                       \
            ushort4 pk = make_ushort4(f2bf(pf[j][0]), f2bf(pf[j][1]),                    \
                                      f2bf(pf[j][2]), f2bf(pf[j][3]));                   \
            *(ushort4*)&Bs[bufw][pl][pf_c[j] * A_ + aseg] = pk;                          \
          } }

    #define CALC_PW(bufw, kk)                                                            \
        { for (int i = tid; i < C2_ * PT_; i += 256) {                                   \
            int d = i >> 5, pl = i & 31;                                                 \
            const float* kv = &kpoS[(d * K_ + (kk)) * 3];                                \
            float s = mdS[pl][0] * kv[0] + mdS[pl][1] * kv[1] + mdS[pl][2] * kv[2];      \
            pwS[bufw][d][pl] = fmaxf(s, 0.f);                                            \
          } }

    // A-fragment loads, straight from global (L2-resident with nt fm loads)
    const unsigned short* awbase = WT + (size_t)(wid * 96 + rowm) * CA_ + quad * 8;
    #define LOAD_A(dst, kk, ch)                                                          \
        { const unsigned short* ap = awbase + (size_t)(kk) * (DR_ * CA_) + (ch) * 32;    \
          _Pragma("unroll")                                                              \
          for (int mt = 0; mt < 6; mt++) dst[mt] = *(const short8*)(ap + mt * 16 * CA_); }

    // small tables
    for (int i = tid; i < PT_ * 3; i += 256) {
        int p = i / 3, c = i % 3;
        mdS[p][c] = md[((size_t)b * P_ + p0 + p) * 3 + c];
    }
    for (int i = tid; i < C2_ * K_ * 3; i += 256) kpoS[i] = kpo[i];
    for (int i = tid; i < DR_; i += 256) biasS[i] = be[i];

    floatx4 acc_o[6][2];
    floatx4 acc_k[6][2];
    #pragma unroll
    for (int mt = 0; mt < 6; mt++)
        #pragma unroll
        for (int nt = 0; nt < 2; nt++) { acc_o[mt][nt] = (floatx4)0.f; acc_k[mt][nt] = (floatx4)0.f; }

    short8 abuf[3][6];   // ring of 3: prefetch distance 2 chunks

    // ---- prologue ----
    LOAD_PF(0);
    __syncthreads();              // tables visible
    LOAD_A(abuf[0], 0, 0);        // chunks 0,1 of k=0 issued BEFORE the big pf batch
    LOAD_A(abuf[1], 0, 1);
    STORE_PF(0);                  // waits pf(0); A-loads are newer -> not drained
    CALC_PW(0, 0);
    LOAD_PF(1);

    for (int k = 0; k < K_; k++) {
        const int buf = k & 1;
        __syncthreads();          // publish Bs[buf], pwS[buf]; retire prior readers

        #pragma unroll
        for (int ch = 0; ch < 12; ch++) {
            if (ch < 10) LOAD_A(abuf[(ch + 2) % 3], k, ch + 2);
            short8 bfr[2];
            #pragma unroll
            for (int nt = 0; nt < 2; nt++)
                bfr[nt] = *(const short8*)(&Bs[buf][nt * 16 + rowm][ch * 32 + quad * 8]);
            const short8* af = abuf[ch % 3];
            #pragma unroll
            for (int mt = 0; mt < 6; mt++)
                #pragma unroll
                for (int nt = 0; nt < 2; nt++)
                    acc_k[mt][nt] = __builtin_amdgcn_mfma_f32_16x16x32_bf16(af[mt], bfr[nt], acc_k[mt][nt], 0, 0, 0);
        }

        // epilogue-k: acc_o += pw[d,p] * acc_k.  d is constant across the 4 acc regs
        // (quads start at r in {0,4,8}) -> one pwS read per (mt,nt), <=2-way banks.
        #pragma unroll
        for (int mt = 0; mt < 6; mt++) {
            const int drb = wid * 96 + mt * 16 + quad * 4;
            const int d = drb / 12;
            #pragma unroll
            for (int nt = 0; nt < 2; nt++) {
                const float pv = pwS[buf][d][nt * 16 + rowm];
                #pragma unroll
                for (int reg = 0; reg < 4; reg++) {
                    acc_o[mt][nt][reg] += pv * acc_k[mt][nt][reg];
                    acc_k[mt][nt][reg] = 0.f;
                }
            }
        }

        // stage k+1 into the other buffer (no barrier: other waves only touch buf)
        if (k + 1 < K_) {
            LOAD_A(abuf[0], k + 1, 0);   // issued before pf batch AND before STORE_PF's
            LOAD_A(abuf[1], k + 1, 1);   //   pf-wait (newer than pf -> can stay in flight)
            STORE_PF(buf ^ 1);           // pf(k+1) landed long ago
            CALC_PW(buf ^ 1, k + 1);
        }
        if (k + 2 < K_) LOAD_PF(k + 2);
    }

    // ---- final: relu(acc_o + bias_eff) -> out[b,d,p,r], float4 non-temporal stores ----
    // each acc quad is 4 consecutive r at fixed (d,p): r0 in {0,4,8}, never crosses d.
    #pragma unroll
    for (int mt = 0; mt < 6; mt++) {
        const int drb = wid * 96 + mt * 16 + quad * 4;
        const int d = drb / 12, r0 = drb - d * 12;
        floatx4 bz;
        #pragma unroll
        for (int reg = 0; reg < 4; reg++) bz[reg] = biasS[drb + reg];
        #pragma unroll
        for (int nt = 0; nt < 2; nt++) {
            const int p = p0 + nt * 16 + rowm;
            floatx4 v = acc_o[mt][nt] + bz;
            #pragma unroll
            for (int reg = 0; reg < 4; reg++) v[reg] = fmaxf(v[reg], 0.f);
            __builtin_nontemporal_store(v,
                (floatx4*)(out + ((((size_t)b * C2_ + d) * P_ + p) * A_ + r0)));
        }
    }
}

// ---------------- launcher ----------------
extern "C" void kernel_launch(void* const* d_in, const int* in_sizes, int n_in,
                              void* d_out, int out_size, void* d_ws, size_t ws_size,
                              hipStream_t stream) {
    const int*   nbr     = (const int*)d_in[0];
    const float* verts   = (const float*)d_in[1];
    const float* fm      = (const float*)d_in[2];
    const float* W       = (const float*)d_in[3];
    const float* bias    = (const float*)d_in[4];
    const float* kpw     = (const float*)d_in[5];
    const float* vs      = (const float*)d_in[6];
    const int*   idx_map = (const int*)d_in[7];
    const int*   tivr    = (const int*)d_in[8];
    const int*   tir     = (const int*)d_in[9];
    const int*   lvl     = (const int*)d_in[10];
    float* out = (float*)d_out;

    char* ws = (char*)d_ws;
    unsigned short* WT2 = (unsigned short*)ws;            // 13*384*384*2 = 3,833,856 B
    float* md_ws  = (float*)(ws + 4000000);               // 196,608 B
    float* kpo_ws = (float*)(ws + 4200000);               // 4,992 B
    float* be_ws  = (float*)(ws + 4210000);               // 1,536 B

    {
        const int TOT = K_ * DR_ * CA_;                   // 1,916,928
        build_wt<<<(TOT + 255) / 256, 256, 0, stream>>>(W, kpw, idx_map, tivr, tir, WT2);
    }
    build_md<<<(B_ * P_) / 256, 256, 0, stream>>>(nbr, verts, md_ws);
    build_kpo<<<7, 64, 0, stream>>>(kpw, idx_map, vs, kpo_ws);
    build_be<<<6, 64, 0, stream>>>(bias, lvl, tivr, be_ws);

    main_gemm<<<B_ * (P_ / PT_), 256, 0, stream>>>(fm, WT2, md_ws, kpo_ws, be_ws, out);
}

// Round 4
// 605.910 us; speedup vs baseline: 1.2355x; 1.2355x over previous
//
#include <hip/hip_runtime.h>
#include <cstdint>
#include <cstddef>

// Problem constants
#define B_   2
#define P_   8192
#define NN_  24
#define C1_  32
#define C2_  32
#define K_   13
#define A_   12
#define DR_  384   // C2_*A_  (rows: d*12+r)
#define CA_  384   // C1_*A_  (cols: c*12+a)
#define PT_  64    // p-tile per block (doubled: halves WT re-read traffic)
#define BPAD 408   // 384 + 24 pad: stride 204 dwords ≡ 12 (mod 32) -> 2-way (free) b128 reads

typedef __attribute__((ext_vector_type(8))) short short8;
typedef __attribute__((ext_vector_type(4))) float floatx4;

__device__ __forceinline__ unsigned short f2bf(float f) {
    union { float f; unsigned int u; } v; v.f = f;
    unsigned int u = v.u;
    return (unsigned short)((u + 0x7fffu + ((u >> 16) & 1u)) >> 16); // RNE
}

// ---------------- prep kernels ----------------

__global__ void build_wt(const float* __restrict__ W, const float* __restrict__ kpw,
                         const int* __restrict__ idx_map, const int* __restrict__ tivr,
                         const int* __restrict__ tir, unsigned short* __restrict__ WT2) {
    int id = blockIdx.x * 256 + threadIdx.x;
    const int TOT = K_ * DR_ * CA_;
    if (id >= TOT) return;
    int ca = id % CA_;
    int t1 = id / CA_;
    int dr = t1 % DR_;
    int k  = t1 / DR_;
    int d = dr / 12, r = dr % 12;
    int c = ca / 12, a = ca % 12;
    int kk = tivr[r * K_ + k];
    int ia = tir[r * A_ + a];
    int m  = idx_map[kk * A_ + ia];
    WT2[id] = f2bf(W[(d * C1_ + c) * 36 + m] * kpw[d * 36 + m]);
}

__global__ void build_md(const int* __restrict__ nbr, const float* __restrict__ verts,
                         float* __restrict__ md) {
    int t = blockIdx.x * 256 + threadIdx.x;
    if (t >= B_ * P_) return;
    const float* vp = verts + (size_t)t * 3;
    float vx = vp[0], vy = vp[1], vz = vp[2];
    int b = t / P_;
    const int* np = nbr + (size_t)t * NN_;
    float ax = 0.f, ay = 0.f, az = 0.f;
    for (int n = 0; n < NN_; n++) {
        int j = np[n];
        const float* vq = verts + ((size_t)b * P_ + j) * 3;
        float dx = vq[0] - vx, dy = vq[1] - vy, dz = vq[2] - vz;
        float nn = sqrtf(dx * dx + dy * dy + dz * dz);
        float inv = 1.f / fmaxf(nn, 1e-12f);
        ax += dx * inv; ay += dy * inv; az += dz * inv;
    }
    const float s = 1.f / 24.f;
    md[t * 3 + 0] = ax * s; md[t * 3 + 1] = ay * s; md[t * 3 + 2] = az * s;
}

__global__ void build_kpo(const float* __restrict__ kpw, const int* __restrict__ idx_map,
                          const float* __restrict__ vs, float* __restrict__ kpo) {
    int t = blockIdx.x * 64 + threadIdx.x;
    if (t >= C2_ * K_) return;
    int d = t / K_, k = t % K_;
    float x = 0.f, y = 0.f, z = 0.f;
    for (int a = 0; a < A_; a++) {
        float w = kpw[d * 36 + idx_map[k * A_ + a]];
        x += w * vs[a * 3 + 0]; y += w * vs[a * 3 + 1]; z += w * vs[a * 3 + 2];
    }
    float nn = sqrtf(x * x + y * y + z * z);
    float inv = 1.f / fmaxf(nn, 1e-12f);
    kpo[t * 3 + 0] = x * inv; kpo[t * 3 + 1] = y * inv; kpo[t * 3 + 2] = z * inv;
}

__global__ void build_be(const float* __restrict__ bias, const int* __restrict__ lvl,
                         const int* __restrict__ tivr, float* __restrict__ be) {
    int t = blockIdx.x * 64 + threadIdx.x;
    if (t >= DR_) return;
    int d = t / 12, r = t % 12;
    float s = 0.f;
    for (int k = 0; k < K_; k++) s += bias[d * 5 + lvl[tivr[r * K_ + k]]];
    be[t] = s;
}

// ---------------- main fused kernel ----------------
// grid = 256 blocks (b x 128 p-tiles of 64), 512 threads (8 waves), 1 block/CU.
// PT=64 halves total WT re-read traffic (256 x 3.83 MB = 0.98 GB) and doubles
// MFMA work per A-fragment load (nt=4).
// Pipeline (per k iteration):
//   barrier -> STORE_PF/CALC_PW for k+1 into buf^1 (pf regs freed here)
//   chunk loop: A-prefetch dist 2 (ring 3), pf(k+2) issued at ch=6..8, MFMA
//   epilogue: acc_o += pw * acc_k
// STORE_PF at the TOP (not end) so the ch=6..8 pf(k+2) loads never clobber
// pf before fm(k+1) is staged (the round-3 correctness bug).
__global__ __launch_bounds__(512, 2) void main_gemm(
    const float* __restrict__ fm, const unsigned short* __restrict__ WT,
    const float* __restrict__ md, const float* __restrict__ kpo,
    const float* __restrict__ be, float* __restrict__ out) {

    __shared__ __attribute__((aligned(16))) unsigned short Bs[2][PT_][BPAD]; // 104448 B
    __shared__ float pwS[2][C2_][PT_ + 1];  // [buf][d][p]  16640 B
    __shared__ float mdS[PT_][3];           // 768 B
    __shared__ float kpoS[C2_ * K_ * 3];    // 4992 B
    __shared__ float biasS[DR_];            // 1536 B

    const int tid  = threadIdx.x;
    const int bid  = blockIdx.x;
    const int b    = bid >> 7;
    const int p0   = (bid & 127) << 6;
    const int lane = tid & 63;
    const int wid  = tid >> 6;        // 0..7, owns rows wid*48 .. wid*48+47
    const int rowm = lane & 15;
    const int quad = lane >> 4;

    // this thread's fm-slice decomposition (12 float4 per thread, coalesced)
    // slice for (b,k): [C1][64 p][12 a] floats = 24576 floats = 6144 float4 = 12*512
    floatx4 pf[12];
    int pf_c[12], pf_jj[12];
    #pragma unroll
    for (int j = 0; j < 12; j++) {
        int f = j * 512 + tid;
        pf_c[j]  = f / 192;           // 192 float4 per c
        pf_jj[j] = f - pf_c[j] * 192;
    }

    #define LOAD_PF_PART(kk, j0, j1)                                                     \
        do { _Pragma("unroll")                                                           \
          for (int j = (j0); j < (j1); j++) {                                            \
            const floatx4* src = (const floatx4*)(fm +                                   \
                ((((size_t)b * C1_ + pf_c[j]) * K_ + (kk)) * P_ + p0) * A_) + pf_jj[j];  \
            pf[j] = *src;                                                                \
          } } while (0)
    #define LOAD_PF(kk) LOAD_PF_PART(kk, 0, 12)

    #define STORE_PF(bufw)                                                               \
        do { _Pragma("unroll")                                                           \
          for (int j = 0; j < 12; j++) {                                                 \
            int pl = pf_jj[j] / 3, aseg = (pf_jj[j] - pl * 3) * 4;                       \
            ushort4 pk = make_ushort4(f2bf(pf[j][0]), f2bf(pf[j][1]),                    \
                                      f2bf(pf[j][2]), f2bf(pf[j][3]));                   \
            *(ushort4*)&Bs[bufw][pl][pf_c[j] * A_ + aseg] = pk;                          \
          } } while (0)

    #define CALC_PW(bufw, kk)                                                            \
        do { _Pragma("unroll")                                                           \
          for (int it = 0; it < 4; it++) {                                               \
            int i = it * 512 + tid;                                                      \
            int d = i >> 6, pl = i & 63;                                                 \
            const float* kv = &kpoS[(d * K_ + (kk)) * 3];                                \
            float s = mdS[pl][0] * kv[0] + mdS[pl][1] * kv[1] + mdS[pl][2] * kv[2];      \
            pwS[bufw][d][pl] = fmaxf(s, 0.f);                                            \
          } } while (0)

    // A-fragment loads straight from global (L2/L3); wave owns 48 rows (mt=0..2)
    const unsigned short* awbase = WT + (size_t)(wid * 48 + rowm) * CA_ + quad * 8;
    #define LOAD_A(dst, kk, ch)                                                          \
        do { const unsigned short* ap = awbase + (size_t)(kk) * (DR_ * CA_) + (ch) * 32; \
          _Pragma("unroll")                                                              \
          for (int mt = 0; mt < 3; mt++) dst[mt] = *(const short8*)(ap + mt * 16 * CA_); \
        } while (0)

    // small tables
    for (int i = tid; i < PT_ * 3; i += 512) {
        int p = i / 3, c = i % 3;
        mdS[p][c] = md[((size_t)b * P_ + p0 + p) * 3 + c];
    }
    for (int i = tid; i < C2_ * K_ * 3; i += 512) kpoS[i] = kpo[i];
    for (int i = tid; i < DR_; i += 512) biasS[i] = be[i];

    floatx4 acc_o[3][4];
    floatx4 acc_k[3][4];
    #pragma unroll
    for (int mt = 0; mt < 3; mt++)
        #pragma unroll
        for (int nt = 0; nt < 4; nt++) { acc_o[mt][nt] = (floatx4)0.f; acc_k[mt][nt] = (floatx4)0.f; }

    short8 abuf[3][3];   // ring of 3: prefetch distance 2 chunks

    // ---- prologue ----
    LOAD_PF(0);
    __syncthreads();              // tables visible
    LOAD_A(abuf[0], 0, 0);        // chunks 0,1 of k=0 issued BEFORE STORE_PF's pf-wait
    LOAD_A(abuf[1], 0, 1);
    STORE_PF(0);                  // waits pf(0); A-loads are newer -> stay in flight
    CALC_PW(0, 0);
    LOAD_PF(1);                   // pf <- fm(1)

    for (int k = 0; k < K_; k++) {
        const int buf = k & 1;
        __syncthreads();          // publish Bs[buf], pwS[buf]; retire buf^1 readers

        // stage k+1 into buf^1 NOW, before ch=6..8 reuse the pf registers.
        // Race-free: iteration k only reads Bs[buf]/pwS[buf]; prior readers of
        // buf^1 retired at the barrier above.  The pf(k+1) wait does not drain
        // the A-loads issued after it (prev iter ch=9..11).
        if (k + 1 < K_) {
            STORE_PF(buf ^ 1);
            CALC_PW(buf ^ 1, k + 1);
        }

        #pragma unroll
        for (int ch = 0; ch < 12; ch++) {
            // A prefetch, distance 2; tail chunks pull k+1's chunks 0,1
            if (ch < 10) {
                LOAD_A(abuf[(ch + 2) % 3], k, ch + 2);
            } else if (k + 1 < K_) {
                LOAD_A(abuf[(ch + 2) % 3], k + 1, ch - 10);   // ch=10->abuf[0], 11->abuf[1]
            }
            // pf(k+2) spread over chunks 6..8 (pf regs free: staged at loop top)
            if (k + 2 < K_) {
                if (ch == 6)      { LOAD_PF_PART(k + 2, 0, 4); }
                else if (ch == 7) { LOAD_PF_PART(k + 2, 4, 8); }
                else if (ch == 8) { LOAD_PF_PART(k + 2, 8, 12); }
            }
            short8 bfr[4];
            #pragma unroll
            for (int nt = 0; nt < 4; nt++)
                bfr[nt] = *(const short8*)(&Bs[buf][nt * 16 + rowm][ch * 32 + quad * 8]);
            const short8* af = abuf[ch % 3];
            #pragma unroll
            for (int mt = 0; mt < 3; mt++)
                #pragma unroll
                for (int nt = 0; nt < 4; nt++)
                    acc_k[mt][nt] = __builtin_amdgcn_mfma_f32_16x16x32_bf16(af[mt], bfr[nt], acc_k[mt][nt], 0, 0, 0);
        }

        // epilogue-k: acc_o += pw[d,p] * acc_k  (d constant across the 4 acc regs)
        #pragma unroll
        for (int mt = 0; mt < 3; mt++) {
            const int drb = wid * 48 + mt * 16 + quad * 4;
            const int d = drb / 12;
            #pragma unroll
            for (int nt = 0; nt < 4; nt++) {
                const float pv = pwS[buf][d][nt * 16 + rowm];
                #pragma unroll
                for (int reg = 0; reg < 4; reg++) {
                    acc_o[mt][nt][reg] += pv * acc_k[mt][nt][reg];
                    acc_k[mt][nt][reg] = 0.f;
                }
            }
        }
    }

    // ---- final: relu(acc_o + bias_eff) -> out[b,d,p,r], float4 stores ----
    #pragma unroll
    for (int mt = 0; mt < 3; mt++) {
        const int drb = wid * 48 + mt * 16 + quad * 4;
        const int d = drb / 12, r0 = drb - d * 12;   // r0 in {0,4,8}, never crosses d
        floatx4 bz;
        #pragma unroll
        for (int reg = 0; reg < 4; reg++) bz[reg] = biasS[drb + reg];
        #pragma unroll
        for (int nt = 0; nt < 4; nt++) {
            const int p = p0 + nt * 16 + rowm;
            floatx4 v = acc_o[mt][nt] + bz;
            #pragma unroll
            for (int reg = 0; reg < 4; reg++) v[reg] = fmaxf(v[reg], 0.f);
            *(floatx4*)(out + ((((size_t)b * C2_ + d) * P_ + p) * A_ + r0)) = v;
        }
    }
}

// ---------------- launcher ----------------
extern "C" void kernel_launch(void* const* d_in, const int* in_sizes, int n_in,
                              void* d_out, int out_size, void* d_ws, size_t ws_size,
                              hipStream_t stream) {
    const int*   nbr     = (const int*)d_in[0];
    const float* verts   = (const float*)d_in[1];
    const float* fm      = (const float*)d_in[2];
    const float* W       = (const float*)d_in[3];
    const float* bias    = (const float*)d_in[4];
    const float* kpw     = (const float*)d_in[5];
    const float* vs      = (const float*)d_in[6];
    const int*   idx_map = (const int*)d_in[7];
    const int*   tivr    = (const int*)d_in[8];
    const int*   tir     = (const int*)d_in[9];
    const int*   lvl     = (const int*)d_in[10];
    float* out = (float*)d_out;

    char* ws = (char*)d_ws;
    unsigned short* WT2 = (unsigned short*)ws;            // 13*384*384*2 = 3,833,856 B
    float* md_ws  = (float*)(ws + 4000000);               // 196,608 B
    float* kpo_ws = (float*)(ws + 4200000);               // 4,992 B
    float* be_ws  = (float*)(ws + 4210000);               // 1,536 B

    {
        const int TOT = K_ * DR_ * CA_;                   // 1,916,928
        build_wt<<<(TOT + 255) / 256, 256, 0, stream>>>(W, kpw, idx_map, tivr, tir, WT2);
    }
    build_md<<<(B_ * P_) / 256, 256, 0, stream>>>(nbr, verts, md_ws);
    build_kpo<<<7, 64, 0, stream>>>(kpw, idx_map, vs, kpo_ws);
    build_be<<<6, 64, 0, stream>>>(bias, lvl, tivr, be_ws);

    main_gemm<<<B_ * (P_ / PT_), 512, 0, stream>>>(fm, WT2, md_ws, kpo_ws, be_ws, out);
}